// Round 1
// baseline (223.433 us; speedup 1.0000x reference)
//
#include <hip/hip_runtime.h>
#include <hip/hip_bf16.h>

#define B_  16
#define NQ_ 512
#define NK_ 1024
#define CQ_ 128
#define H_  8
#define D_  64
#define HD_ 512   // H*D

typedef __attribute__((ext_vector_type(8))) short short8;
typedef __attribute__((ext_vector_type(4))) float floatx4;

__device__ __forceinline__ short f2bf(float f) {
    union { float f; unsigned u; } x; x.f = f;
    unsigned r = (x.u + 0x7fffu + ((x.u >> 16) & 1u)) >> 16;  // RNE
    return (short)r;
}

// ---- Stage 0: W[128][512] fp32 -> Wt[512][128] bf16 (transposed) ----
__global__ void wt_kernel(const float* __restrict__ W, short* __restrict__ Wt) {
    int idx = blockIdx.x * blockDim.x + threadIdx.x;   // 0..65535
    int k = idx >> 9;          // input row (K)
    int n = idx & (HD_ - 1);   // output col (N)
    Wt[n * CQ_ + k] = f2bf(W[idx]);                    // coalesced read
}

// ---- Stage 1: projection GEMM  X[M,128] @ W[128,512] + b  (bf16 MFMA) ----
// transposed==0: out[((b*H+h)*rows + r)*64 + d]   (q, k)
// transposed==1: out[((b*H+h)*64 + d)*NK + r]     (vT)
__global__ __launch_bounds__(256) void proj_kernel(
    const float* __restrict__ X, const short* __restrict__ Wt,
    const float* __restrict__ bias, short* __restrict__ out,
    int rshift, float scale, int transposed)
{
    const int w    = threadIdx.x >> 6;
    const int lane = threadIdx.x & 63;
    const int l15  = lane & 15, quad = lane >> 4;
    const int mbase = blockIdx.x * 64 + w * 16;
    const int nbase = blockIdx.y * 64;
    const int rows  = 1 << rshift;

    // A fragments: 16 rows x K=128 (4 chunks of 32)
    short8 afr[4];
    const float* xrow = X + (size_t)(mbase + l15) * CQ_;
    #pragma unroll
    for (int kt = 0; kt < 4; ++kt) {
        #pragma unroll
        for (int j = 0; j < 8; ++j)
            afr[kt][j] = f2bf(xrow[kt * 32 + quad * 8 + j]);
    }

    #pragma unroll
    for (int nt = 0; nt < 4; ++nt) {
        const int n = nbase + nt * 16 + l15;
        floatx4 acc = {0.f, 0.f, 0.f, 0.f};
        const short8* wrow = (const short8*)(Wt + (size_t)n * CQ_);
        #pragma unroll
        for (int kt = 0; kt < 4; ++kt) {
            short8 bfr = wrow[kt * 4 + quad];   // W^T[n][kt*32+quad*8 ..+8]
            acc = __builtin_amdgcn_mfma_f32_16x16x32_bf16(afr[kt], bfr, acc, 0, 0, 0);
        }
        const float bv = bias[n];
        const int h = n >> 6, d = n & 63;
        #pragma unroll
        for (int i = 0; i < 4; ++i) {
            const int m = mbase + quad * 4 + i;          // C/D row
            const int b = m >> rshift, r = m & (rows - 1);
            const float val = (acc[i] + bv) * scale;
            size_t o;
            if (!transposed) o = ((size_t)(b * H_ + h) * rows + r) * D_ + d;
            else             o = ((size_t)(b * H_ + h) * D_ + d) * NK_ + r;
            out[o] = f2bf(val);
        }
    }
}

// ---- Stage 2: flash attention ----
// grid: B*H*(NQ/64) = 1024 blocks, 256 threads (4 waves x 16 q-rows)
__global__ __launch_bounds__(256) void attn_kernel(
    const short* __restrict__ qs, const short* __restrict__ ks,
    const short* __restrict__ vt, const float* __restrict__ cmask,
    float* __restrict__ out)
{
    // padded row stride 72 elems (144B) breaks the 128B power-of-2 bank stride
    __shared__ __align__(16) short ksh[64 * 72];
    __shared__ __align__(16) short vsh[64 * 72];
    __shared__ __align__(16) short psh[4 * 16 * 72];

    const int tid = threadIdx.x;
    const int w = tid >> 6, lane = tid & 63;
    const int l15 = lane & 15, quad = lane >> 4;

    const int bx   = blockIdx.x;          // b*64 + h*8 + qblk
    const int qblk = bx & 7;
    const int h    = (bx >> 3) & 7;
    const int b    = bx >> 6;

    const size_t bh = (size_t)(b * H_ + h);
    const short* qb  = qs + (bh * NQ_ + (size_t)qblk * 64 + w * 16) * D_;
    const short* kb_ = ks + bh * NK_ * D_;
    const short* vb  = vt + bh * D_ * NK_;
    const float* mk  = cmask + (size_t)b * NK_;

    // Q fragments (rows = this wave's 16 q rows, K=64 in 2 chunks), pre-scaled by 1/8
    short8 qa[2];
    {
        const short8* qrow = (const short8*)(qb + (size_t)l15 * D_);
        qa[0] = qrow[quad];
        qa[1] = qrow[4 + quad];
    }

    float m_i[4], l_i[4];
    floatx4 o_acc[4];
    #pragma unroll
    for (int i = 0; i < 4; ++i) { m_i[i] = -1e30f; l_i[i] = 0.f; }
    #pragma unroll
    for (int dt = 0; dt < 4; ++dt) o_acc[dt] = (floatx4){0.f, 0.f, 0.f, 0.f};

    for (int kbase = 0; kbase < NK_; kbase += 64) {
        __syncthreads();   // previous tile's PV reads of vsh complete
        // cooperative stage: ksh[key][d], vsh[d][key]  (64x64 each)
        #pragma unroll
        for (int r = 0; r < 2; ++r) {
            const int vi  = tid + r * 256;       // 0..511
            const int row = vi >> 3, c8 = (vi & 7) * 8;
            *(short8*)&ksh[row * 72 + c8] =
                *(const short8*)(kb_ + (size_t)(kbase + row) * D_ + c8);
            *(short8*)&vsh[row * 72 + c8] =
                *(const short8*)(vb + (size_t)row * NK_ + kbase + c8);
        }
        __syncthreads();

        // S = q . k^T  (16q x 64k per wave)
        floatx4 sc[4];
        #pragma unroll
        for (int nt = 0; nt < 4; ++nt) {
            floatx4 acc = {0.f, 0.f, 0.f, 0.f};
            short8 b0 = *(const short8*)&ksh[(nt * 16 + l15) * 72 + quad * 8];
            short8 b1 = *(const short8*)&ksh[(nt * 16 + l15) * 72 + 32 + quad * 8];
            acc = __builtin_amdgcn_mfma_f32_16x16x32_bf16(qa[0], b0, acc, 0, 0, 0);
            acc = __builtin_amdgcn_mfma_f32_16x16x32_bf16(qa[1], b1, acc, 0, 0, 0);
            sc[nt] = acc;
        }
        // additive mask
        #pragma unroll
        for (int nt = 0; nt < 4; ++nt) {
            const float mv = (mk[kbase + nt * 16 + l15] - 1.0f) * 100000.0f;
            #pragma unroll
            for (int i = 0; i < 4; ++i) sc[nt][i] += mv;
        }
        // online softmax (row = quad*4+i, owned by the quad's 16 lanes)
        float pv[4][4];   // [nt][i]
        #pragma unroll
        for (int i = 0; i < 4; ++i) {
            float tm = fmaxf(fmaxf(sc[0][i], sc[1][i]), fmaxf(sc[2][i], sc[3][i]));
            #pragma unroll
            for (int s = 1; s < 16; s <<= 1) tm = fmaxf(tm, __shfl_xor(tm, s));
            const float mnew  = fmaxf(m_i[i], tm);
            const float alpha = __expf(m_i[i] - mnew);
            float psum = 0.f;
            #pragma unroll
            for (int nt = 0; nt < 4; ++nt) {
                const float p = __expf(sc[nt][i] - mnew);
                pv[nt][i] = p; psum += p;
            }
            #pragma unroll
            for (int s = 1; s < 16; s <<= 1) psum += __shfl_xor(psum, s);
            m_i[i] = mnew;
            l_i[i] = l_i[i] * alpha + psum;
            #pragma unroll
            for (int dt = 0; dt < 4; ++dt) o_acc[dt][i] *= alpha;
        }
        // P -> LDS (C-layout scatter) to re-read in A-layout
        #pragma unroll
        for (int nt = 0; nt < 4; ++nt)
            #pragma unroll
            for (int i = 0; i < 4; ++i)
                psh[(w * 16 + quad * 4 + i) * 72 + nt * 16 + l15] = f2bf(pv[nt][i]);
        __syncthreads();
        // O += P . V   (K-dim = 64 keys, N = 64 d in 4 tiles)
        #pragma unroll
        for (int kt = 0; kt < 2; ++kt) {
            short8 pa = *(const short8*)&psh[(w * 16 + l15) * 72 + kt * 32 + quad * 8];
            #pragma unroll
            for (int dt = 0; dt < 4; ++dt) {
                short8 bvf = *(const short8*)&vsh[(dt * 16 + l15) * 72 + kt * 32 + quad * 8];
                o_acc[dt] = __builtin_amdgcn_mfma_f32_16x16x32_bf16(pa, bvf, o_acc[dt], 0, 0, 0);
            }
        }
    }

    // epilogue: normalize and store fp32
    #pragma unroll
    for (int i = 0; i < 4; ++i) {
        const float inv = 1.0f / l_i[i];
        const int qr = qblk * 64 + w * 16 + quad * 4 + i;
        float* orow = out + ((size_t)b * NQ_ + qr) * HD_ + h * D_;
        #pragma unroll
        for (int dt = 0; dt < 4; ++dt)
            orow[dt * 16 + l15] = o_acc[dt][i] * inv;
    }
}

extern "C" void kernel_launch(void* const* d_in, const int* in_sizes, int n_in,
                              void* d_out, int out_size, void* d_ws, size_t ws_size,
                              hipStream_t stream) {
    const float* query = (const float*)d_in[0];
    const float* key   = (const float*)d_in[1];
    const float* cmask = (const float*)d_in[2];
    const float* Wq    = (const float*)d_in[3];
    const float* bq    = (const float*)d_in[4];
    const float* Wk    = (const float*)d_in[5];
    const float* bk    = (const float*)d_in[6];
    const float* Wv    = (const float*)d_in[7];
    const float* bv    = (const float*)d_in[8];
    float* out = (float*)d_out;

    char* ws = (char*)d_ws;
    short* qs  = (short*)(ws);                           // 8 MB  (B*H*NQ*D bf16)
    short* ks  = (short*)(ws + (size_t)( 8u << 20));     // 16 MB (B*H*NK*D)
    short* vt  = (short*)(ws + (size_t)(24u << 20));     // 16 MB (B*H*D*NK)
    short* wqt = (short*)(ws + (size_t)(40u << 20));                  // 128 KB
    short* wkt = (short*)(ws + (size_t)(40u << 20) + 131072 * 2);     // 128 KB
    short* wvt = (short*)(ws + (size_t)(40u << 20) + 131072 * 4);     // 128 KB

    // Stage 0: weight transpose+convert (tiny)
    wt_kernel<<<dim3(256), dim3(256), 0, stream>>>(Wq, wqt);
    wt_kernel<<<dim3(256), dim3(256), 0, stream>>>(Wk, wkt);
    wt_kernel<<<dim3(256), dim3(256), 0, stream>>>(Wv, wvt);

    // Stage 1: projections (q scaled by 1/sqrt(64)=0.125)
    proj_kernel<<<dim3(128, 8), dim3(256), 0, stream>>>(query, wqt, bq, qs, 9,  0.125f, 0);
    proj_kernel<<<dim3(256, 8), dim3(256), 0, stream>>>(key,   wkt, bk, ks, 10, 1.0f,   0);
    proj_kernel<<<dim3(256, 8), dim3(256), 0, stream>>>(key,   wvt, bv, vt, 10, 1.0f,   1);

    // Stage 2: attention
    attn_kernel<<<dim3(B_ * H_ * (NQ_ / 64)), dim3(256), 0, stream>>>(qs, ks, vt, cmask, out);
}

// Round 2
// 184.064 us; speedup vs baseline: 1.2139x; 1.2139x over previous
//
#include <hip/hip_runtime.h>
#include <hip/hip_bf16.h>

#define B_  16
#define NQ_ 512
#define NK_ 1024
#define CQ_ 128
#define H_  8
#define D_  64
#define HD_ 512   // H*D

typedef __attribute__((ext_vector_type(8))) short short8;
typedef __attribute__((ext_vector_type(4))) float floatx4;

__device__ __forceinline__ short f2bf(float f) {
    union { float f; unsigned u; } x; x.f = f;
    unsigned r = (x.u + 0x7fffu + ((x.u >> 16) & 1u)) >> 16;  // RNE
    return (short)r;
}
__device__ __forceinline__ int f2bf_pk(float a, float b) {   // packed RNE (v_cvt_pk_bf16_f32)
    __hip_bfloat162 h = __float22bfloat162_rn(make_float2(a, b));
    int r; __builtin_memcpy(&r, &h, 4); return r;
}

// ---- Stage 0: three W[128][512] fp32 -> Wt[512][128] bf16, one launch ----
__global__ void wt3_kernel(const float* __restrict__ W0, const float* __restrict__ W1,
                           const float* __restrict__ W2, short* __restrict__ T0,
                           short* __restrict__ T1, short* __restrict__ T2) {
    int gi = blockIdx.x * blockDim.x + threadIdx.x;   // 0..196607
    int sel = gi >> 16;
    int idx = gi & 65535;
    const float* W = sel == 0 ? W0 : (sel == 1 ? W1 : W2);
    short* T = sel == 0 ? T0 : (sel == 1 ? T1 : T2);
    int k = idx >> 9;          // input row (K)
    int n = idx & (HD_ - 1);   // output col (N)
    T[n * CQ_ + k] = f2bf(W[idx]);                    // coalesced read
}

// ---- Stage 1: projection GEMM  X[M,128] @ W[128,512] + b  (bf16 MFMA) ----
// tile: 128 (M) x 64 (N=one head) per 256-thread block; fully coalesced I/O.
// transposed==0: out[((b*H+h)*rows + r)*64 + d]   (q, k)
// transposed==1: out[((b*H+h)*64 + d)*NK + r]     (vT)
__global__ __launch_bounds__(256) void proj2_kernel(
    const float* __restrict__ X, const short* __restrict__ Wt,
    const float* __restrict__ bias, short* __restrict__ out,
    int rshift, float scale, int transposed)
{
    __shared__ __align__(16) short xsh[128 * 136];   // [m][k], pad to 136
    __shared__ __align__(16) short csh[9216];        // [m][d] s72  or  [d][m] s136

    const int tid  = threadIdx.x;
    const int w    = tid >> 6, lane = tid & 63;
    const int l15  = lane & 15, quad = lane >> 4;
    const int mbase = blockIdx.x * 128;
    const int nbase = blockIdx.y * 64;

    // --- stage X tile (128x128 fp32 -> bf16 LDS), coalesced float4 ---
    #pragma unroll
    for (int it = 0; it < 16; ++it) {
        const int idx = it * 256 + tid;              // 0..4095
        const int row = idx >> 5, c4 = (idx & 31) << 2;
        float4 xv = *(const float4*)(X + (size_t)(mbase + row) * CQ_ + c4);
        *(int2*)&xsh[row * 136 + c4] = make_int2(f2bf_pk(xv.x, xv.y), f2bf_pk(xv.z, xv.w));
    }

    // --- B fragments from global (L2-hot, shared across all blocks) ---
    short8 bfr[4][4];
    #pragma unroll
    for (int nt = 0; nt < 4; ++nt) {
        const short8* wrow = (const short8*)(Wt + (size_t)(nbase + nt * 16 + l15) * CQ_);
        #pragma unroll
        for (int kt = 0; kt < 4; ++kt) bfr[nt][kt] = wrow[kt * 4 + quad];
    }
    __syncthreads();

    // --- MFMA: wave w covers rows [w*32, w*32+32) ---
    floatx4 acc[2][4];
    #pragma unroll
    for (int mt = 0; mt < 2; ++mt) {
        short8 afr[4];
        const int mrow = w * 32 + mt * 16 + l15;
        #pragma unroll
        for (int kt = 0; kt < 4; ++kt)
            afr[kt] = *(const short8*)&xsh[mrow * 136 + kt * 32 + quad * 8];
        #pragma unroll
        for (int nt = 0; nt < 4; ++nt) {
            floatx4 a = {0.f, 0.f, 0.f, 0.f};
            #pragma unroll
            for (int kt = 0; kt < 4; ++kt)
                a = __builtin_amdgcn_mfma_f32_16x16x32_bf16(afr[kt], bfr[nt][kt], a, 0, 0, 0);
            acc[mt][nt] = a;
        }
    }

    // --- epilogue through LDS for coalesced stores ---
    #pragma unroll
    for (int mt = 0; mt < 2; ++mt)
        #pragma unroll
        for (int nt = 0; nt < 4; ++nt) {
            const float bv = bias[nbase + nt * 16 + l15];
            #pragma unroll
            for (int i = 0; i < 4; ++i) {
                const short s = f2bf((acc[mt][nt][i] + bv) * scale);
                const int m = w * 32 + mt * 16 + quad * 4 + i;
                const int n = nt * 16 + l15;
                if (!transposed) csh[m * 72 + n]  = s;
                else             csh[n * 136 + m] = s;
            }
        }
    __syncthreads();

    const int rows = 1 << rshift;
    const int b  = mbase >> rshift;
    const int r0 = mbase & (rows - 1);
    const size_t bh = (size_t)(b * H_ + blockIdx.y);
    if (!transposed) {
        short* dst = out + (bh * rows + r0) * D_;    // contiguous 8192-elem region
        #pragma unroll
        for (int it = 0; it < 4; ++it) {
            const int idx = it * 256 + tid;          // 0..1023
            const int row = idx >> 3, c8 = (idx & 7) * 8;
            *(short8*)(dst + idx * 8) = *(const short8*)&csh[row * 72 + c8];
        }
    } else {
        short* dst = out + bh * D_ * NK_ + r0;       // 64 rows x 128 cols, row stride NK
        #pragma unroll
        for (int it = 0; it < 4; ++it) {
            const int idx = it * 256 + tid;
            const int row = idx >> 4, c8 = (idx & 15) * 8;
            *(short8*)(dst + (size_t)row * NK_ + c8) = *(const short8*)&csh[row * 136 + c8];
        }
    }
}

// ---- Stage 2: flash attention ----
// grid: B*H*(NQ/64) = 1024 blocks, 256 threads (4 waves x 16 q-rows)
// scores arrive in log2 units (q pre-scaled by 0.125*log2e), so exp == v_exp_f32.
__global__ __launch_bounds__(256) void attn_kernel(
    const short* __restrict__ qs, const short* __restrict__ ks,
    const short* __restrict__ vt, const float* __restrict__ cmask,
    float* __restrict__ out)
{
    __shared__ __align__(16) short ksh[64 * 72];
    __shared__ __align__(16) short vsh[64 * 72];
    __shared__ __align__(16) short psh[4 * 16 * 72];

    const int tid = threadIdx.x;
    const int w = tid >> 6, lane = tid & 63;
    const int l15 = lane & 15, quad = lane >> 4;

    const int bx   = blockIdx.x;          // b*64 + h*8 + qblk
    const int qblk = bx & 7;
    const int h    = (bx >> 3) & 7;
    const int b    = bx >> 6;

    const size_t bh = (size_t)(b * H_ + h);
    const short* qb  = qs + (bh * NQ_ + (size_t)qblk * 64 + w * 16) * D_;
    const short* kb_ = ks + bh * NK_ * D_;
    const short* vb  = vt + bh * D_ * NK_;
    const float* mk  = cmask + (size_t)b * NK_;

    short8 qa[2];
    {
        const short8* qrow = (const short8*)(qb + (size_t)l15 * D_);
        qa[0] = qrow[quad];
        qa[1] = qrow[4 + quad];
    }

    float m_i[4], l_i[4];
    floatx4 o_acc[4];
    #pragma unroll
    for (int i = 0; i < 4; ++i) { m_i[i] = -1e30f; l_i[i] = 0.f; }
    #pragma unroll
    for (int dt = 0; dt < 4; ++dt) o_acc[dt] = (floatx4){0.f, 0.f, 0.f, 0.f};

    for (int kbase = 0; kbase < NK_; kbase += 64) {
        __syncthreads();   // previous tile's ksh/vsh/psh reads complete
        #pragma unroll
        for (int r = 0; r < 2; ++r) {
            const int vi  = tid + r * 256;       // 0..511
            const int row = vi >> 3, c8 = (vi & 7) * 8;
            *(short8*)&ksh[row * 72 + c8] =
                *(const short8*)(kb_ + (size_t)(kbase + row) * D_ + c8);
            *(short8*)&vsh[row * 72 + c8] =
                *(const short8*)(vb + (size_t)row * NK_ + kbase + c8);
        }
        __syncthreads();

        // S = q . k^T  (16q x 64k per wave), log2 units
        floatx4 sc[4];
        #pragma unroll
        for (int nt = 0; nt < 4; ++nt) {
            floatx4 acc = {0.f, 0.f, 0.f, 0.f};
            short8 b0 = *(const short8*)&ksh[(nt * 16 + l15) * 72 + quad * 8];
            short8 b1 = *(const short8*)&ksh[(nt * 16 + l15) * 72 + 32 + quad * 8];
            acc = __builtin_amdgcn_mfma_f32_16x16x32_bf16(qa[0], b0, acc, 0, 0, 0);
            acc = __builtin_amdgcn_mfma_f32_16x16x32_bf16(qa[1], b1, acc, 0, 0, 0);
            sc[nt] = acc;
        }
        #pragma unroll
        for (int nt = 0; nt < 4; ++nt) {
            const float mv = (mk[kbase + nt * 16 + l15] - 1.0f) * 144269.504f; // 1e5*log2e
            #pragma unroll
            for (int i = 0; i < 4; ++i) sc[nt][i] += mv;
        }
        // online softmax in log2 domain
        float pv[4][4];   // [nt][i]
        #pragma unroll
        for (int i = 0; i < 4; ++i) {
            float tm = fmaxf(fmaxf(sc[0][i], sc[1][i]), fmaxf(sc[2][i], sc[3][i]));
            #pragma unroll
            for (int s = 1; s < 16; s <<= 1) tm = fmaxf(tm, __shfl_xor(tm, s));
            const float mnew  = fmaxf(m_i[i], tm);
            const float alpha = __builtin_amdgcn_exp2f(m_i[i] - mnew);
            float psum = 0.f;
            #pragma unroll
            for (int nt = 0; nt < 4; ++nt) {
                const float p = __builtin_amdgcn_exp2f(sc[nt][i] - mnew);
                pv[nt][i] = p; psum += p;
            }
            #pragma unroll
            for (int s = 1; s < 16; s <<= 1) psum += __shfl_xor(psum, s);
            m_i[i] = mnew;
            l_i[i] = l_i[i] * alpha + psum;
            #pragma unroll
            for (int dt = 0; dt < 4; ++dt) o_acc[dt][i] *= alpha;
        }
        // P -> LDS (wave-private rows; same-wave DS ordering, no barrier needed)
        #pragma unroll
        for (int nt = 0; nt < 4; ++nt)
            #pragma unroll
            for (int i = 0; i < 4; ++i)
                psh[(w * 16 + quad * 4 + i) * 72 + nt * 16 + l15] = f2bf(pv[nt][i]);
        // O += P . V
        #pragma unroll
        for (int kt = 0; kt < 2; ++kt) {
            short8 pa = *(const short8*)&psh[(w * 16 + l15) * 72 + kt * 32 + quad * 8];
            #pragma unroll
            for (int dt = 0; dt < 4; ++dt) {
                short8 bvf = *(const short8*)&vsh[(dt * 16 + l15) * 72 + kt * 32 + quad * 8];
                o_acc[dt] = __builtin_amdgcn_mfma_f32_16x16x32_bf16(pa, bvf, o_acc[dt], 0, 0, 0);
            }
        }
    }

    #pragma unroll
    for (int i = 0; i < 4; ++i) {
        const float inv = 1.0f / l_i[i];
        const int qr = qblk * 64 + w * 16 + quad * 4 + i;
        float* orow = out + ((size_t)b * NQ_ + qr) * HD_ + h * D_;
        #pragma unroll
        for (int dt = 0; dt < 4; ++dt)
            orow[dt * 16 + l15] = o_acc[dt][i] * inv;
    }
}

extern "C" void kernel_launch(void* const* d_in, const int* in_sizes, int n_in,
                              void* d_out, int out_size, void* d_ws, size_t ws_size,
                              hipStream_t stream) {
    const float* query = (const float*)d_in[0];
    const float* key   = (const float*)d_in[1];
    const float* cmask = (const float*)d_in[2];
    const float* Wq    = (const float*)d_in[3];
    const float* bq    = (const float*)d_in[4];
    const float* Wk    = (const float*)d_in[5];
    const float* bk    = (const float*)d_in[6];
    const float* Wv    = (const float*)d_in[7];
    const float* bv    = (const float*)d_in[8];
    float* out = (float*)d_out;

    char* ws = (char*)d_ws;
    short* qs  = (short*)(ws);                           // 8 MB  (B*H*NQ*D bf16)
    short* ks  = (short*)(ws + (size_t)( 8u << 20));     // 16 MB (B*H*NK*D)
    short* vt  = (short*)(ws + (size_t)(24u << 20));     // 16 MB (B*H*D*NK)
    short* wqt = (short*)(ws + (size_t)(40u << 20));                  // 128 KB
    short* wkt = (short*)(ws + (size_t)(40u << 20) + 131072 * 2);     // 128 KB
    short* wvt = (short*)(ws + (size_t)(40u << 20) + 131072 * 4);     // 128 KB

    wt3_kernel<<<dim3(768), dim3(256), 0, stream>>>(Wq, Wk, Wv, wqt, wkt, wvt);

    // q pre-scaled by 1/sqrt(64) * log2(e) so attention works in exp2 domain
    const float qscale = 0.125f * 1.44269504f;
    proj2_kernel<<<dim3( 64, 8), dim3(256), 0, stream>>>(query, wqt, bq, qs, 9,  qscale, 0);
    proj2_kernel<<<dim3(128, 8), dim3(256), 0, stream>>>(key,   wkt, bk, ks, 10, 1.0f,   0);
    proj2_kernel<<<dim3(128, 8), dim3(256), 0, stream>>>(key,   wvt, bv, vt, 10, 1.0f,   1);

    attn_kernel<<<dim3(B_ * H_ * (NQ_ / 64)), dim3(256), 0, stream>>>(qs, ks, vt, cmask, out);
}

// Round 3
// 157.901 us; speedup vs baseline: 1.4150x; 1.1657x over previous
//
#include <hip/hip_runtime.h>
#include <hip/hip_bf16.h>

#define B_  16
#define NQ_ 512
#define NK_ 1024
#define CQ_ 128
#define H_  8
#define D_  64
#define HD_ 512   // H*D

typedef __attribute__((ext_vector_type(8))) short short8;
typedef __attribute__((ext_vector_type(4))) float floatx4;

__device__ __forceinline__ short f2bf(float f) {
    union { float f; unsigned u; } x; x.f = f;
    unsigned r = (x.u + 0x7fffu + ((x.u >> 16) & 1u)) >> 16;  // RNE
    return (short)r;
}
__device__ __forceinline__ int f2bf_pk(float a, float b) {   // packed RNE (v_cvt_pk_bf16_f32)
    __hip_bfloat162 h = __float22bfloat162_rn(make_float2(a, b));
    int r; __builtin_memcpy(&r, &h, 4); return r;
}

// ---- Stage 0: three W[128][512] fp32 -> Wt[512][128] bf16, one launch ----
__global__ void wt3_kernel(const float* __restrict__ W0, const float* __restrict__ W1,
                           const float* __restrict__ W2, short* __restrict__ T0,
                           short* __restrict__ T1, short* __restrict__ T2) {
    int gi = blockIdx.x * blockDim.x + threadIdx.x;   // 0..196607
    int sel = gi >> 16;
    int idx = gi & 65535;
    const float* W = sel == 0 ? W0 : (sel == 1 ? W1 : W2);
    short* T = sel == 0 ? T0 : (sel == 1 ? T1 : T2);
    int k = idx >> 9;          // input row (K)
    int n = idx & (HD_ - 1);   // output col (N)
    T[n * CQ_ + k] = f2bf(W[idx]);                    // coalesced read
}

// ---- Stage 1: fused q/k/v projection GEMM  X[M,128] @ W[128,512] + b ----
// blockIdx.x: [0,64) q | [64,192) k | [192,320) v-transposed; blockIdx.y = head
__global__ __launch_bounds__(256) void proj3_kernel(
    const float* __restrict__ query, const float* __restrict__ key_,
    const short* __restrict__ wqt, const short* __restrict__ wkt,
    const short* __restrict__ wvt,
    const float* __restrict__ bq, const float* __restrict__ bk,
    const float* __restrict__ bv,
    short* __restrict__ qs, short* __restrict__ ks, short* __restrict__ vt,
    float qscale)
{
    __shared__ __align__(16) short xsh[128 * 136];   // X tile; reused as C tile
    short* csh = xsh;                                // epilogue reuse (after barrier)

    int bx = blockIdx.x;
    const float* X; const short* Wt; const float* bias; short* out;
    int rshift, transposed; float scale;
    if (bx < 64)       { X = query; Wt = wqt; bias = bq; out = qs; rshift = 9;  scale = qscale; transposed = 0; }
    else if (bx < 192) { bx -= 64;  X = key_; Wt = wkt; bias = bk; out = ks; rshift = 10; scale = 1.0f; transposed = 0; }
    else               { bx -= 192; X = key_; Wt = wvt; bias = bv; out = vt; rshift = 10; scale = 1.0f; transposed = 1; }

    const int tid  = threadIdx.x;
    const int w    = tid >> 6, lane = tid & 63;
    const int l15  = lane & 15, quad = lane >> 4;
    const int mbase = bx * 128;
    const int nbase = blockIdx.y * 64;

    // --- stage X tile (128x128 fp32 -> bf16 LDS), coalesced float4 ---
    #pragma unroll
    for (int it = 0; it < 16; ++it) {
        const int idx = it * 256 + tid;              // 0..4095
        const int row = idx >> 5, c4 = (idx & 31) << 2;
        float4 xv = *(const float4*)(X + (size_t)(mbase + row) * CQ_ + c4);
        *(int2*)&xsh[row * 136 + c4] = make_int2(f2bf_pk(xv.x, xv.y), f2bf_pk(xv.z, xv.w));
    }

    // --- B fragments from global (L2-hot) ---
    short8 bfr[4][4];
    #pragma unroll
    for (int nt = 0; nt < 4; ++nt) {
        const short8* wrow = (const short8*)(Wt + (size_t)(nbase + nt * 16 + l15) * CQ_);
        #pragma unroll
        for (int kt = 0; kt < 4; ++kt) bfr[nt][kt] = wrow[kt * 4 + quad];
    }
    __syncthreads();

    // --- MFMA: wave w covers rows [w*32, w*32+32) ---
    floatx4 acc[2][4];
    #pragma unroll
    for (int mt = 0; mt < 2; ++mt) {
        short8 afr[4];
        const int mrow = w * 32 + mt * 16 + l15;
        #pragma unroll
        for (int kt = 0; kt < 4; ++kt)
            afr[kt] = *(const short8*)&xsh[mrow * 136 + kt * 32 + quad * 8];
        #pragma unroll
        for (int nt = 0; nt < 4; ++nt) {
            floatx4 a = {0.f, 0.f, 0.f, 0.f};
            #pragma unroll
            for (int kt = 0; kt < 4; ++kt)
                a = __builtin_amdgcn_mfma_f32_16x16x32_bf16(afr[kt], bfr[nt][kt], a, 0, 0, 0);
            acc[mt][nt] = a;
        }
    }
    __syncthreads();   // all xsh reads done before csh overwrite

    // --- epilogue through LDS for coalesced stores ---
    #pragma unroll
    for (int mt = 0; mt < 2; ++mt)
        #pragma unroll
        for (int nt = 0; nt < 4; ++nt) {
            const float bvv = bias[nbase + nt * 16 + l15];
            #pragma unroll
            for (int i = 0; i < 4; ++i) {
                const short s = f2bf((acc[mt][nt][i] + bvv) * scale);
                const int m = w * 32 + mt * 16 + quad * 4 + i;
                const int n = nt * 16 + l15;
                if (!transposed) csh[m * 72 + n]  = s;
                else             csh[n * 136 + m] = s;
            }
        }
    __syncthreads();

    const int rows = 1 << rshift;
    const int b  = mbase >> rshift;
    const int r0 = mbase & (rows - 1);
    const size_t bh = (size_t)(b * H_ + blockIdx.y);
    if (!transposed) {
        short* dst = out + (bh * rows + r0) * D_;    // contiguous 8192-elem region
        #pragma unroll
        for (int it = 0; it < 4; ++it) {
            const int idx = it * 256 + tid;          // 0..1023
            const int row = idx >> 3, c8 = (idx & 7) * 8;
            *(short8*)(dst + idx * 8) = *(const short8*)&csh[row * 72 + c8];
        }
    } else {
        short* dst = out + bh * D_ * NK_ + r0;       // 64 rows x 128 cols, row stride NK
        #pragma unroll
        for (int it = 0; it < 4; ++it) {
            const int idx = it * 256 + tid;
            const int row = idx >> 4, c8 = (idx & 15) * 8;
            *(short8*)(dst + (size_t)row * NK_ + c8) = *(const short8*)&csh[row * 136 + c8];
        }
    }
}

// ---- Stage 2: flash attention, S^T form ----
// grid: B*H*(NQ/128) = 512 blocks, 256 threads (4 waves), 32 q-rows per wave.
// S^T = K·Q^T : each lane owns 16 keys for one query (l15) -> register-local
// softmax reduction + packed b64 P-writes. Scores in log2 units.
__global__ __launch_bounds__(256) void attn_kernel(
    const short* __restrict__ qs, const short* __restrict__ ks,
    const short* __restrict__ vt, const float* __restrict__ cmask,
    float* __restrict__ out)
{
    __shared__ __align__(16) short ksh[64 * 72];    // [key][d]
    __shared__ __align__(16) short vsh[64 * 72];    // [d][key]
    __shared__ __align__(16) short psh[128 * 72];   // [qrow][key], wave-private rows

    const int tid = threadIdx.x;
    const int w = tid >> 6, lane = tid & 63;
    const int l15 = lane & 15, quad = lane >> 4;

    const int bx   = blockIdx.x;          // b*32 + h*4 + qblk
    const int qblk = bx & 3;
    const int h    = (bx >> 2) & 7;
    const int b    = bx >> 5;

    const size_t bh = (size_t)(b * H_ + h);
    const short* qb  = qs + (bh * NQ_ + (size_t)qblk * 128 + w * 32) * D_;
    const short* kb_ = ks + bh * NK_ * D_;
    const short* vb  = vt + bh * D_ * NK_;
    const float* mk  = cmask + (size_t)b * NK_;

    // Q fragments as B-operand: B[k=d][n=query l15]
    short8 qa[2][2];
    #pragma unroll
    for (int g = 0; g < 2; ++g) {
        const short8* qrow = (const short8*)(qb + (size_t)(g * 16 + l15) * D_);
        qa[g][0] = qrow[quad];
        qa[g][1] = qrow[4 + quad];
    }

    float m_i[2] = {-1e30f, -1e30f}, l_i[2] = {0.f, 0.f};
    floatx4 o_acc[2][4];
    #pragma unroll
    for (int g = 0; g < 2; ++g)
        #pragma unroll
        for (int dt = 0; dt < 4; ++dt) o_acc[g][dt] = (floatx4){0.f, 0.f, 0.f, 0.f};

    for (int kbase = 0; kbase < NK_; kbase += 64) {
        __syncthreads();   // previous tile's LDS reads complete
        #pragma unroll
        for (int r = 0; r < 2; ++r) {
            const int vi  = tid + r * 256;       // 0..511
            const int row = vi >> 3, c8 = (vi & 7) * 8;
            *(short8*)&ksh[row * 72 + c8] =
                *(const short8*)(kb_ + (size_t)(kbase + row) * D_ + c8);
            *(short8*)&vsh[row * 72 + c8] =
                *(const short8*)(vb + (size_t)row * NK_ + kbase + c8);
        }
        __syncthreads();

        // K A-fragments: A[m=key][k=d] — shared across both q-groups
        short8 ka[4][2];
        #pragma unroll
        for (int nt = 0; nt < 4; ++nt) {
            ka[nt][0] = *(const short8*)&ksh[(nt * 16 + l15) * 72 + quad * 8];
            ka[nt][1] = *(const short8*)&ksh[(nt * 16 + l15) * 72 + 32 + quad * 8];
        }
        // additive mask per key (this lane's 16 keys), log2 units
        float mv[4][4];
        #pragma unroll
        for (int nt = 0; nt < 4; ++nt) {
            float4 m4 = *(const float4*)(mk + kbase + nt * 16 + quad * 4);
            mv[nt][0] = (m4.x - 1.0f) * 144269.504f;
            mv[nt][1] = (m4.y - 1.0f) * 144269.504f;
            mv[nt][2] = (m4.z - 1.0f) * 144269.504f;
            mv[nt][3] = (m4.w - 1.0f) * 144269.504f;
        }

        #pragma unroll
        for (int g = 0; g < 2; ++g) {
            // S^T = K·Q^T : D[m=key][n=query]
            floatx4 st[4];
            #pragma unroll
            for (int nt = 0; nt < 4; ++nt) {
                floatx4 a = {0.f, 0.f, 0.f, 0.f};
                a = __builtin_amdgcn_mfma_f32_16x16x32_bf16(ka[nt][1], qa[g][1], a, 0, 0, 0);
                a = __builtin_amdgcn_mfma_f32_16x16x32_bf16(ka[nt][0], qa[g][0], a, 0, 0, 0);
                st[nt] = a;
            }
            #pragma unroll
            for (int nt = 0; nt < 4; ++nt)
                #pragma unroll
                for (int i = 0; i < 4; ++i) st[nt][i] += mv[nt][i];

            // online softmax: keys live in regs (16/lane) + quad dimension
            float tm = st[0][0];
            #pragma unroll
            for (int nt = 0; nt < 4; ++nt)
                #pragma unroll
                for (int i = 0; i < 4; ++i) tm = fmaxf(tm, st[nt][i]);
            tm = fmaxf(tm, __shfl_xor(tm, 16));
            tm = fmaxf(tm, __shfl_xor(tm, 32));
            const float mnew  = fmaxf(m_i[g], tm);
            const float alpha = __builtin_amdgcn_exp2f(m_i[g] - mnew);
            float p[4][4], psum = 0.f;
            #pragma unroll
            for (int nt = 0; nt < 4; ++nt)
                #pragma unroll
                for (int i = 0; i < 4; ++i) {
                    p[nt][i] = __builtin_amdgcn_exp2f(st[nt][i] - mnew);
                    psum += p[nt][i];
                }
            psum += __shfl_xor(psum, 16);
            psum += __shfl_xor(psum, 32);
            m_i[g] = mnew;
            l_i[g] = l_i[g] * alpha + psum;
            // broadcast alpha from query=l15 layout to o_acc row layout
            #pragma unroll
            for (int i = 0; i < 4; ++i) {
                const float ai = __shfl(alpha, quad * 4 + i);
                #pragma unroll
                for (int dt = 0; dt < 4; ++dt) o_acc[g][dt][i] *= ai;
            }
            // P -> LDS: packed b64, keys contiguous (wave-private rows)
            #pragma unroll
            for (int nt = 0; nt < 4; ++nt) {
                int2 pk = make_int2(f2bf_pk(p[nt][0], p[nt][1]), f2bf_pk(p[nt][2], p[nt][3]));
                *(int2*)&psh[(w * 32 + g * 16 + l15) * 72 + nt * 16 + quad * 4] = pk;
            }
        }

        // O += P·V  (V B-fragments shared across q-groups)
        short8 bv8[2][4];
        #pragma unroll
        for (int kt = 0; kt < 2; ++kt)
            #pragma unroll
            for (int dt = 0; dt < 4; ++dt)
                bv8[kt][dt] = *(const short8*)&vsh[(dt * 16 + l15) * 72 + kt * 32 + quad * 8];
        #pragma unroll
        for (int g = 0; g < 2; ++g)
            #pragma unroll
            for (int kt = 0; kt < 2; ++kt) {
                short8 pa = *(const short8*)&psh[(w * 32 + g * 16 + l15) * 72 + kt * 32 + quad * 8];
                #pragma unroll
                for (int dt = 0; dt < 4; ++dt)
                    o_acc[g][dt] = __builtin_amdgcn_mfma_f32_16x16x32_bf16(pa, bv8[kt][dt], o_acc[g][dt], 0, 0, 0);
            }
    }

    // epilogue
    #pragma unroll
    for (int g = 0; g < 2; ++g) {
        const float linv = 1.0f / l_i[g];
        #pragma unroll
        for (int i = 0; i < 4; ++i) {
            const float li = __shfl(linv, quad * 4 + i);
            const int qr = qblk * 128 + w * 32 + g * 16 + quad * 4 + i;
            float* orow = out + ((size_t)b * NQ_ + qr) * HD_ + h * D_;
            #pragma unroll
            for (int dt = 0; dt < 4; ++dt)
                orow[dt * 16 + l15] = o_acc[g][dt][i] * li;
        }
    }
}

extern "C" void kernel_launch(void* const* d_in, const int* in_sizes, int n_in,
                              void* d_out, int out_size, void* d_ws, size_t ws_size,
                              hipStream_t stream) {
    const float* query = (const float*)d_in[0];
    const float* key   = (const float*)d_in[1];
    const float* cmask = (const float*)d_in[2];
    const float* Wq    = (const float*)d_in[3];
    const float* bq    = (const float*)d_in[4];
    const float* Wk    = (const float*)d_in[5];
    const float* bk    = (const float*)d_in[6];
    const float* Wv    = (const float*)d_in[7];
    const float* bv    = (const float*)d_in[8];
    float* out = (float*)d_out;

    char* ws = (char*)d_ws;
    short* qs  = (short*)(ws);                           // 8 MB  (B*H*NQ*D bf16)
    short* ks  = (short*)(ws + (size_t)( 8u << 20));     // 16 MB (B*H*NK*D)
    short* vt  = (short*)(ws + (size_t)(24u << 20));     // 16 MB (B*H*D*NK)
    short* wqt = (short*)(ws + (size_t)(40u << 20));                  // 128 KB
    short* wkt = (short*)(ws + (size_t)(40u << 20) + 131072 * 2);     // 128 KB
    short* wvt = (short*)(ws + (size_t)(40u << 20) + 131072 * 4);     // 128 KB

    wt3_kernel<<<dim3(768), dim3(256), 0, stream>>>(Wq, Wk, Wv, wqt, wkt, wvt);

    // q pre-scaled by 1/sqrt(64) * log2(e) so attention works in exp2 domain
    const float qscale = 0.125f * 1.44269504f;
    proj3_kernel<<<dim3(320, 8), dim3(256), 0, stream>>>(
        query, key, wqt, wkt, wvt, bq, bk, bv, qs, ks, vt, qscale);

    attn_kernel<<<dim3(B_ * H_ * (NQ_ / 128)), dim3(256), 0, stream>>>(qs, ks, vt, cmask, out);
}